// Round 7
// baseline (1095.630 us; speedup 1.0000x reference)
//
#include <hip/hip_runtime.h>
#include <hip/hip_bf16.h>

#define NTOK 49
#define DIM 384
#define HEADS 12
#define SCALE 0.17677669529663687f

typedef __attribute__((ext_vector_type(8))) short bf16x8;
typedef __attribute__((ext_vector_type(4))) float f32x4;

#define MFMA16(a, b, c) __builtin_amdgcn_mfma_f32_16x16x32_bf16((a), (b), (c), 0, 0, 0)

__device__ __forceinline__ short f2bf(float f) {
  __hip_bfloat16 h = __float2bfloat16(f);
  return __builtin_bit_cast(short, h);
}

// Full-K=32 fragment from two K=16 C-tile slices: element j<4 = slice0 value at
// d16 = 4g+j, j>=4 = slice1 at d16 = 4g+(j-4). Exact when A and B frags use the
// same relabel (each of the 32 k-indices appears exactly once on both sides).
__device__ __forceinline__ bf16x8 pack8(f32x4 a, f32x4 b) {
  bf16x8 r;
#pragma unroll
  for (int i = 0; i < 4; ++i) { r[i] = f2bf(a[i]); r[i + 4] = f2bf(b[i]); }
  return r;
}

// ws layout:
//   wqT  : short [384][384]          elem off 0        (Wq^T row-major: [n][k])
//   wkvT : short [768][384]          elem off 147456   (rows 0-383 K, 384-767 V)
//   wpT  : short [384][384]          elem off 442368
//   biasq: float [12][49][52]        byte off 1179648  ([h][q][k], k padded 49->52)
#define WQT_OFF   0
#define WKVT_OFF  147456
#define WPT_OFF   442368
#define BIAS_BYTE_OFF 1179648
#define BIAS_RL   52

__global__ void prep_kernel(const float* __restrict__ qw, const float* __restrict__ kvw,
                            const float* __restrict__ pw, const float* __restrict__ bt,
                            short* __restrict__ wsS, float* __restrict__ biasq) {
  int id = blockIdx.x * 256 + threadIdx.x;
  const int SZ1 = 384 * 384;
  const int SZ2 = 768 * 384;
  const int SZ3 = 384 * 384;
  if (id < SZ1) {
    int n = id / 384, k = id % 384;
    wsS[WQT_OFF + id] = f2bf(qw[k * 384 + n]);
  } else if (id < SZ1 + SZ2) {
    int t = id - SZ1; int n = t / 384, k = t % 384;
    wsS[WKVT_OFF + t] = f2bf(kvw[k * 768 + n]);
  } else if (id < SZ1 + SZ2 + SZ3) {
    int t = id - (SZ1 + SZ2); int n = t / 384, k = t % 384;
    wsS[WPT_OFF + t] = f2bf(pw[k * 384 + n]);
  } else if (id < SZ1 + SZ2 + SZ3 + HEADS * NTOK * BIAS_RL) {
    int t = id - (SZ1 + SZ2 + SZ3);
    int h = t / (NTOK * BIAS_RL); int rc = t % (NTOK * BIAS_RL);
    int q = rc / BIAS_RL, c = rc % BIAS_RL;
    float v = 0.0f;
    if (c < NTOK) {
      int idx = ((q / 7 - c / 7) + 6) * 13 + ((q % 7 - c % 7) + 6);
      v = bt[idx * HEADS + h];
    }
    biasq[t] = v;
  }
}

// LDS (shorts). Row stride 392 -> 784B = 196 dw == 4 mod 32: 16-row b128 frag
// reads land 2 lanes/bank (free).
#define X_OFF    0            // [49][392]  x_body
#define XE_OFF   19208        // [49][392]  x_edge; reused as OALL after Q phase
#define LDS_ELEMS 38416
#define LDS_BYTES (LDS_ELEMS * 2)   // 76832 B -> 2 blocks/CU

// launch_bounds 2nd arg = min BLOCKS per CU (CUDA semantics; empirically
// cap = 512/(ceil(waves_per_block/4)*arg): (512,4)->64, (384,3)->84, (768,6)->40).
// (384,2): worst-case 4 waves/SIMD -> 128 VGPR cap, guarantees 2 blocks/CU.
__global__ __launch_bounds__(384, 2)
void fused_kernel(const float* __restrict__ xe, const float* __restrict__ xb,
                  const float* __restrict__ qb, const float* __restrict__ kvb,
                  const float* __restrict__ pb,
                  const short* __restrict__ wqT, const short* __restrict__ wkvT,
                  const short* __restrict__ wpT, const float* __restrict__ biasq,
                  float* __restrict__ out) {
  extern __shared__ short lds[];
  short* X    = lds + X_OFF;     // x_body
  short* XE   = lds + XE_OFF;    // x_edge
  short* OALL = XE;              // O tiles after Q phase (XE dead)

  const int b   = blockIdx.x;
  const int tid = threadIdx.x;
  const int u   = tid >> 6;      // wave 0..5, owns heads 2u, 2u+1
  const int l   = tid & 63;
  const int m16 = l & 15;
  const int g   = l >> 4;

  const f32x4 zf = {0.f, 0.f, 0.f, 0.f};

  // ---- stage x_edge -> XE and x_body -> X (bf16, 8B packed writes) ----
  const float* xew = xe + (size_t)b * (NTOK * DIM);
  const float* xbw = xb + (size_t)b * (NTOK * DIM);
  for (int i4 = tid; i4 < 2 * (NTOK * DIM / 4); i4 += 384) {
    int eb = i4 < (NTOK * DIM / 4);
    int e = (eb ? i4 : i4 - NTOK * DIM / 4) * 4;
    const float* src = eb ? xew : xbw;
    short* dst = eb ? XE : X;
    int r = e / DIM, c = e % DIM;
    float4 v = *(const float4*)(src + e);
    ushort4 s;
    s.x = (unsigned short)f2bf(v.x); s.y = (unsigned short)f2bf(v.y);
    s.z = (unsigned short)f2bf(v.z); s.w = (unsigned short)f2bf(v.w);
    *(ushort4*)&dst[r * 392 + c] = s;
  }
  __syncthreads();   // [#1]

  // ================= Q^T GEMM for heads 2u, 2u+1 (wave-private) ============
  // qc[hh][dt][tb]: C[d_local = g*4+i][tok = tb*16+m16]
  f32x4 qc[2][2][4];
#pragma unroll
  for (int hh = 0; hh < 2; ++hh)
#pragma unroll
    for (int dt = 0; dt < 2; ++dt)
#pragma unroll
      for (int tb = 0; tb < 4; ++tb) qc[hh][dt][tb] = zf;

#pragma unroll
  for (int kk = 0; kk < 12; ++kk) {
    const int ko = kk * 32 + g * 8;
    bf16x8 xv[4];
#pragma unroll
    for (int tb = 0; tb < 4; ++tb) {
      int tr = tb * 16 + m16; tr = tr < 49 ? tr : 48;
      xv[tb] = *(const bf16x8*)(&XE[tr * 392 + ko]);
    }
#pragma unroll
    for (int hh = 0; hh < 2; ++hh)
#pragma unroll
      for (int dt = 0; dt < 2; ++dt) {
        bf16x8 aw = *(const bf16x8*)(wqT + (size_t)((2 * u + hh) * 32 + dt * 16 + m16) * 384 + ko);
#pragma unroll
        for (int tb = 0; tb < 4; ++tb) qc[hh][dt][tb] = MFMA16(aw, xv[tb], qc[hh][dt][tb]);
      }
  }
  // fold bias+scale, merge dt slices into full-K frags; lane m16 = q
  bf16x8 qfr[2][4];
#pragma unroll
  for (int hh = 0; hh < 2; ++hh) {
    const int h = 2 * u + hh;
    float4 t0 = *(const float4*)(qb + h * 32 + g * 4);
    float4 t1 = *(const float4*)(qb + h * 32 + 16 + g * 4);
    f32x4 b0 = {t0.x, t0.y, t0.z, t0.w};
    f32x4 b1 = {t1.x, t1.y, t1.z, t1.w};
#pragma unroll
    for (int qt = 0; qt < 4; ++qt)
      qfr[hh][qt] = pack8((qc[hh][0][qt] + b0) * SCALE, (qc[hh][1][qt] + b1) * SCALE);
  }
  __syncthreads();   // [#2] all XE reads done -> XE becomes OALL

  // ================= per head: K GEMM, V GEMM (split passes), attention =====
#pragma unroll
  for (int hh = 0; hh < 2; ++hh) {
    const int h = 2 * u + hh;

    // ---- K pass (kc only: 32 VGPRs live) ----
    bf16x8 kfr[4];
    {
      f32x4 kc[2][4];
#pragma unroll
      for (int dt = 0; dt < 2; ++dt)
#pragma unroll
        for (int tb = 0; tb < 4; ++tb) kc[dt][tb] = zf;
#pragma unroll
      for (int kk = 0; kk < 12; ++kk) {
        const int ko = kk * 32 + g * 8;
        bf16x8 xv[4];
#pragma unroll
        for (int tb = 0; tb < 4; ++tb) {
          int tr = tb * 16 + m16; tr = tr < 49 ? tr : 48;
          xv[tb] = *(const bf16x8*)(&X[tr * 392 + ko]);
        }
        bf16x8 kw[2];
#pragma unroll
        for (int dt = 0; dt < 2; ++dt)
          kw[dt] = *(const bf16x8*)(wkvT + (size_t)(h * 32 + dt * 16 + m16) * 384 + ko);
#pragma unroll
        for (int dt = 0; dt < 2; ++dt)
#pragma unroll
          for (int tb = 0; tb < 4; ++tb) kc[dt][tb] = MFMA16(kw[dt], xv[tb], kc[dt][tb]);
      }
      float4 t0 = *(const float4*)(kvb + h * 32 + g * 4);
      float4 t1 = *(const float4*)(kvb + h * 32 + 16 + g * 4);
      f32x4 b0 = {t0.x, t0.y, t0.z, t0.w};
      f32x4 b1 = {t1.x, t1.y, t1.z, t1.w};
#pragma unroll
      for (int tb = 0; tb < 4; ++tb) kfr[tb] = pack8(kc[0][tb] + b0, kc[1][tb] + b1);
    }

    // ---- V pass (vc only: 32 VGPRs live) ----
    bf16x8 vfr[2][2];
    {
      f32x4 vc[4][2];
#pragma unroll
      for (int tb = 0; tb < 4; ++tb)
#pragma unroll
        for (int db = 0; db < 2; ++db) vc[tb][db] = zf;
#pragma unroll
      for (int kk = 0; kk < 12; ++kk) {
        const int ko = kk * 32 + g * 8;
        bf16x8 xv[4];
#pragma unroll
        for (int tb = 0; tb < 4; ++tb) {
          int tr = tb * 16 + m16; tr = tr < 49 ? tr : 48;
          xv[tb] = *(const bf16x8*)(&X[tr * 392 + ko]);
        }
        bf16x8 vw[2];
#pragma unroll
        for (int db = 0; db < 2; ++db)
          vw[db] = *(const bf16x8*)(wkvT + (size_t)(384 + h * 32 + db * 16 + m16) * 384 + ko);
#pragma unroll
        for (int tb = 0; tb < 4; ++tb)
#pragma unroll
          for (int db = 0; db < 2; ++db) vc[tb][db] = MFMA16(xv[tb], vw[db], vc[tb][db]);
      }
#pragma unroll
      for (int db = 0; db < 2; ++db) {
        float vbv = kvb[384 + h * 32 + db * 16 + m16];
        f32x4 bv = {vbv, vbv, vbv, vbv};
#pragma unroll
        for (int t = 0; t < 2; ++t)
          vfr[t][db] = pack8(vc[2 * t][db] + bv, vc[2 * t + 1][db] + bv);
      }
    }

    // ---- attention per q-tile: S (1 MFMA/k-tile), softmax, PV ----
#pragma unroll
    for (int qt = 0; qt < 4; ++qt) {
      int q = qt * 16 + m16; int qcl = q < 49 ? q : 48;
      const float* bq = biasq + (size_t)(h * NTOK + qcl) * BIAS_RL;
      f32x4 s[4];
#pragma unroll
      for (int tb = 0; tb < 4; ++tb) s[tb] = MFMA16(kfr[tb], qfr[hh][qt], zf);

      float sv[4][4];
      float mx = -3.0e38f;
#pragma unroll
      for (int tb = 0; tb < 4; ++tb) {
        int k0 = tb * 16 + g * 4;
        int kcl = k0 <= 48 ? k0 : 48;     // bias row padded to 52, offset 48 is safe
        float4 bv = *(const float4*)(bq + kcl);
        sv[tb][0] = (k0 + 0 < 49) ? s[tb][0] + bv.x : -3.0e38f;
        sv[tb][1] = (k0 + 1 < 49) ? s[tb][1] + bv.y : -3.0e38f;
        sv[tb][2] = (k0 + 2 < 49) ? s[tb][2] + bv.z : -3.0e38f;
        sv[tb][3] = (k0 + 3 < 49) ? s[tb][3] + bv.w : -3.0e38f;
        mx = fmaxf(mx, fmaxf(fmaxf(sv[tb][0], sv[tb][1]), fmaxf(sv[tb][2], sv[tb][3])));
      }
      mx = fmaxf(mx, __shfl_xor(mx, 16));
      mx = fmaxf(mx, __shfl_xor(mx, 32));
      float sum = 0.f;
#pragma unroll
      for (int tb = 0; tb < 4; ++tb)
#pragma unroll
        for (int i = 0; i < 4; ++i) {
          float e = __expf(sv[tb][i] - mx);
          sv[tb][i] = e;
          sum += e;
        }
      sum += __shfl_xor(sum, 16);
      sum += __shfl_xor(sum, 32);
      float inv = 1.0f / sum;

      bf16x8 pfr[2];
#pragma unroll
      for (int t = 0; t < 2; ++t) {
        f32x4 lo = {sv[2 * t][0] * inv, sv[2 * t][1] * inv, sv[2 * t][2] * inv, sv[2 * t][3] * inv};
        f32x4 hi = {sv[2 * t + 1][0] * inv, sv[2 * t + 1][1] * inv, sv[2 * t + 1][2] * inv, sv[2 * t + 1][3] * inv};
        pfr[t] = pack8(lo, hi);
      }
      f32x4 o0 = zf, o1 = zf;
      o0 = MFMA16(pfr[0], vfr[0][0], o0); o0 = MFMA16(pfr[1], vfr[1][0], o0);
      o1 = MFMA16(pfr[0], vfr[0][1], o1); o1 = MFMA16(pfr[1], vfr[1][1], o1);
#pragma unroll
      for (int i = 0; i < 4; ++i) {
        int r = qt * 16 + g * 4 + i;
        if (r < 49) {
          OALL[r * 392 + h * 32 + m16]      = f2bf(o0[i]);
          OALL[r * 392 + h * 32 + 16 + m16] = f2bf(o1[i]);
        }
      }
    }
  }
  __syncthreads();   // [#3] OALL complete

  // ================= out-projection: wave owns col-tiles u*4..u*4+3 ========
  f32x4 pacc[4][4];
#pragma unroll
  for (int qt = 0; qt < 4; ++qt)
#pragma unroll
    for (int ct = 0; ct < 4; ++ct) pacc[qt][ct] = zf;
#pragma unroll
  for (int kk = 0; kk < 12; ++kk) {
    const int ko = kk * 32 + g * 8;
    bf16x8 af[4];
#pragma unroll
    for (int qt = 0; qt < 4; ++qt) {
      int r = qt * 16 + m16; r = r < 49 ? r : 48;
      af[qt] = *(const bf16x8*)(&OALL[r * 392 + ko]);
    }
#pragma unroll
    for (int ct = 0; ct < 4; ++ct) {
      bf16x8 bw = *(const bf16x8*)(wpT + (size_t)((u * 4 + ct) * 16 + m16) * 384 + ko);
#pragma unroll
      for (int qt = 0; qt < 4; ++qt) pacc[qt][ct] = MFMA16(af[qt], bw, pacc[qt][ct]);
    }
  }
  float* outw = out + (size_t)b * (NTOK * DIM);
#pragma unroll
  for (int ct = 0; ct < 4; ++ct) {
    int col = (u * 4 + ct) * 16 + m16;
    float pbv = pb[col];
#pragma unroll
    for (int qt = 0; qt < 4; ++qt)
#pragma unroll
      for (int i = 0; i < 4; ++i) {
        int r = qt * 16 + g * 4 + i;
        if (r < 49) outw[r * DIM + col] = pacc[qt][ct][i] + pbv;
      }
  }
}

extern "C" void kernel_launch(void* const* d_in, const int* in_sizes, int n_in,
                              void* d_out, int out_size, void* d_ws, size_t ws_size,
                              hipStream_t stream) {
  const float* xe  = (const float*)d_in[0];
  const float* xb  = (const float*)d_in[1];
  const float* qw  = (const float*)d_in[2];
  const float* qb  = (const float*)d_in[3];
  const float* kvw = (const float*)d_in[4];
  const float* kvb = (const float*)d_in[5];
  const float* pw  = (const float*)d_in[6];
  const float* pb  = (const float*)d_in[7];
  const float* bt  = (const float*)d_in[8];
  float* out = (float*)d_out;
  short* wsS = (short*)d_ws;
  float* biasq = (float*)((char*)d_ws + BIAS_BYTE_OFF);

  const int nwin = in_sizes[0] / (NTOK * DIM);

  const int prep_items = 384 * 384 + 768 * 384 + 384 * 384 + HEADS * NTOK * BIAS_RL;
  prep_kernel<<<(prep_items + 255) / 256, 256, 0, stream>>>(qw, kvw, pw, bt, wsS, biasq);

  hipFuncSetAttribute((const void*)fused_kernel,
                      hipFuncAttributeMaxDynamicSharedMemorySize, LDS_BYTES);
  fused_kernel<<<nwin, 384, LDS_BYTES, stream>>>(
      xe, xb, qb, kvb, pb,
      wsS + WQT_OFF, wsS + WKVT_OFF, wsS + WPT_OFF, biasq, out);
}

// Round 8
// 1076.437 us; speedup vs baseline: 1.0178x; 1.0178x over previous
//
#include <hip/hip_runtime.h>
#include <hip/hip_bf16.h>

#define NTOK 49
#define DIM 384
#define HEADS 12
#define SCALE 0.17677669529663687f

typedef __attribute__((ext_vector_type(8))) short bf16x8;
typedef __attribute__((ext_vector_type(4))) float f32x4;

#define MFMA16(a, b, c) __builtin_amdgcn_mfma_f32_16x16x32_bf16((a), (b), (c), 0, 0, 0)

__device__ __forceinline__ short f2bf(float f) {
  __hip_bfloat16 h = __float2bfloat16(f);
  return __builtin_bit_cast(short, h);
}

// Full-K=32 fragment from two K=16 C-tile slices (same relabel on A and B -> exact).
__device__ __forceinline__ bf16x8 pack8(f32x4 a, f32x4 b) {
  bf16x8 r;
#pragma unroll
  for (int i = 0; i < 4; ++i) { r[i] = f2bf(a[i]); r[i + 4] = f2bf(b[i]); }
  return r;
}

// ws layout:
//   wqT  : short [384][384]   elem off 0        (Wq^T row-major [n][k])
//   wkvT : short [768][384]   elem off 147456   (rows 0-383 K, 384-767 V)
//   wpT  : short [384][384]   elem off 442368
//   biasq: float [12][49][52] byte off 1179648
#define WQT_OFF   0
#define WKVT_OFF  147456
#define WPT_OFF   442368
#define BIAS_BYTE_OFF 1179648
#define BIAS_RL   52

__global__ void prep_kernel(const float* __restrict__ qw, const float* __restrict__ kvw,
                            const float* __restrict__ pw, const float* __restrict__ bt,
                            short* __restrict__ wsS, float* __restrict__ biasq) {
  int id = blockIdx.x * 256 + threadIdx.x;
  const int SZ1 = 384 * 384;
  const int SZ2 = 768 * 384;
  const int SZ3 = 384 * 384;
  if (id < SZ1) {
    int n = id / 384, k = id % 384;
    wsS[WQT_OFF + id] = f2bf(qw[k * 384 + n]);
  } else if (id < SZ1 + SZ2) {
    int t = id - SZ1; int n = t / 384, k = t % 384;
    wsS[WKVT_OFF + t] = f2bf(kvw[k * 768 + n]);
  } else if (id < SZ1 + SZ2 + SZ3) {
    int t = id - (SZ1 + SZ2); int n = t / 384, k = t % 384;
    wsS[WPT_OFF + t] = f2bf(pw[k * 384 + n]);
  } else if (id < SZ1 + SZ2 + SZ3 + HEADS * NTOK * BIAS_RL) {
    int t = id - (SZ1 + SZ2 + SZ3);
    int h = t / (NTOK * BIAS_RL); int rc = t % (NTOK * BIAS_RL);
    int q = rc / BIAS_RL, c = rc % BIAS_RL;
    float v = 0.0f;
    if (c < NTOK) {
      int idx = ((q / 7 - c / 7) + 6) * 13 + ((q % 7 - c % 7) + 6);
      v = bt[idx * HEADS + h];
    }
    biasq[t] = v;
  }
}

// LDS (shorts), 4 x [49][392] buffers. Stride 392 shorts = 196 dw == 4 mod 32:
// 16-row b128 frag reads land 2 lanes/bank (free, m136).
//   X0 @ 0, X1 @ 19208 (x_body win0/1); XE0 @ 38416, XE1 @ 57624 (x_edge,
//   reused as OALL0/OALL1 after each window's Q pass).
#define LDS_ELEMS 76832
#define LDS_BYTES (LDS_ELEMS * 2)   // 153664 B -> 1 block/CU, 12 waves

// ---- per-wave building blocks (all state static-indexed -> registers) ----
__device__ __forceinline__ void q_gemm(const short* __restrict__ XE,
                                       const short* __restrict__ wqT,
                                       const float* __restrict__ qb,
                                       int h, int m16, int g, bf16x8 qfr[4]) {
  const f32x4 zf = {0.f, 0.f, 0.f, 0.f};
  f32x4 qc[2][4];
#pragma unroll
  for (int dt = 0; dt < 2; ++dt)
#pragma unroll
    for (int tb = 0; tb < 4; ++tb) qc[dt][tb] = zf;
#pragma unroll
  for (int kk = 0; kk < 12; ++kk) {
    const int ko = kk * 32 + g * 8;
    bf16x8 xv[4];
#pragma unroll
    for (int tb = 0; tb < 4; ++tb) {
      int tr = tb * 16 + m16; tr = tr < 49 ? tr : 48;
      xv[tb] = *(const bf16x8*)(&XE[tr * 392 + ko]);
    }
#pragma unroll
    for (int dt = 0; dt < 2; ++dt) {
      bf16x8 aw = *(const bf16x8*)(wqT + (size_t)(h * 32 + dt * 16 + m16) * 384 + ko);
#pragma unroll
      for (int tb = 0; tb < 4; ++tb) qc[dt][tb] = MFMA16(aw, xv[tb], qc[dt][tb]);
    }
  }
  float4 t0 = *(const float4*)(qb + h * 32 + g * 4);
  float4 t1 = *(const float4*)(qb + h * 32 + 16 + g * 4);
  f32x4 b0 = {t0.x, t0.y, t0.z, t0.w};
  f32x4 b1 = {t1.x, t1.y, t1.z, t1.w};
#pragma unroll
  for (int qt = 0; qt < 4; ++qt)
    qfr[qt] = pack8((qc[0][qt] + b0) * SCALE, (qc[1][qt] + b1) * SCALE);
}

__device__ __forceinline__ void attn_head(const short* __restrict__ X,
                                          short* __restrict__ OALL,
                                          const short* __restrict__ wkvT,
                                          const float* __restrict__ kvb,
                                          const float* __restrict__ biasq,
                                          int h, int m16, int g, const bf16x8 qfr[4]) {
  const f32x4 zf = {0.f, 0.f, 0.f, 0.f};
  // ---- fused K + V GEMM (one X pass) ----
  f32x4 kc[2][4], vc[4][2];
#pragma unroll
  for (int dt = 0; dt < 2; ++dt)
#pragma unroll
    for (int tb = 0; tb < 4; ++tb) kc[dt][tb] = zf;
#pragma unroll
  for (int tb = 0; tb < 4; ++tb)
#pragma unroll
    for (int db = 0; db < 2; ++db) vc[tb][db] = zf;

#pragma unroll
  for (int kk = 0; kk < 12; ++kk) {
    const int ko = kk * 32 + g * 8;
    bf16x8 xv[4];
#pragma unroll
    for (int tb = 0; tb < 4; ++tb) {
      int tr = tb * 16 + m16; tr = tr < 49 ? tr : 48;
      xv[tb] = *(const bf16x8*)(&X[tr * 392 + ko]);
    }
    bf16x8 kw[2], vw[2];
#pragma unroll
    for (int dt = 0; dt < 2; ++dt)
      kw[dt] = *(const bf16x8*)(wkvT + (size_t)(h * 32 + dt * 16 + m16) * 384 + ko);
#pragma unroll
    for (int db = 0; db < 2; ++db)
      vw[db] = *(const bf16x8*)(wkvT + (size_t)(384 + h * 32 + db * 16 + m16) * 384 + ko);
#pragma unroll
    for (int dt = 0; dt < 2; ++dt)
#pragma unroll
      for (int tb = 0; tb < 4; ++tb) kc[dt][tb] = MFMA16(kw[dt], xv[tb], kc[dt][tb]);
#pragma unroll
    for (int tb = 0; tb < 4; ++tb)
#pragma unroll
      for (int db = 0; db < 2; ++db) vc[tb][db] = MFMA16(xv[tb], vw[db], vc[tb][db]);
  }
  bf16x8 kfr[4], vfr[2][2];
  {
    float4 t0 = *(const float4*)(kvb + h * 32 + g * 4);
    float4 t1 = *(const float4*)(kvb + h * 32 + 16 + g * 4);
    f32x4 b0 = {t0.x, t0.y, t0.z, t0.w};
    f32x4 b1 = {t1.x, t1.y, t1.z, t1.w};
#pragma unroll
    for (int tb = 0; tb < 4; ++tb) kfr[tb] = pack8(kc[0][tb] + b0, kc[1][tb] + b1);
  }
#pragma unroll
  for (int db = 0; db < 2; ++db) {
    float vbv = kvb[384 + h * 32 + db * 16 + m16];
    f32x4 bv = {vbv, vbv, vbv, vbv};
#pragma unroll
    for (int t = 0; t < 2; ++t)
      vfr[t][db] = pack8(vc[2 * t][db] + bv, vc[2 * t + 1][db] + bv);
  }

  // ---- per q-tile: S (1 MFMA/k-tile), softmax, PV ----
#pragma unroll
  for (int qt = 0; qt < 4; ++qt) {
    int q = qt * 16 + m16; int qcl = q < 49 ? q : 48;
    const float* bq = biasq + (size_t)(h * NTOK + qcl) * BIAS_RL;
    f32x4 s[4];
#pragma unroll
    for (int tb = 0; tb < 4; ++tb) s[tb] = MFMA16(kfr[tb], qfr[qt], zf);

    float sv[4][4];
    float mx = -3.0e38f;
#pragma unroll
    for (int tb = 0; tb < 4; ++tb) {
      int k0 = tb * 16 + g * 4;
      int kcl = k0 <= 48 ? k0 : 48;     // bias row padded to 52
      float4 bv = *(const float4*)(bq + kcl);
      sv[tb][0] = (k0 + 0 < 49) ? s[tb][0] + bv.x : -3.0e38f;
      sv[tb][1] = (k0 + 1 < 49) ? s[tb][1] + bv.y : -3.0e38f;
      sv[tb][2] = (k0 + 2 < 49) ? s[tb][2] + bv.z : -3.0e38f;
      sv[tb][3] = (k0 + 3 < 49) ? s[tb][3] + bv.w : -3.0e38f;
      mx = fmaxf(mx, fmaxf(fmaxf(sv[tb][0], sv[tb][1]), fmaxf(sv[tb][2], sv[tb][3])));
    }
    mx = fmaxf(mx, __shfl_xor(mx, 16));
    mx = fmaxf(mx, __shfl_xor(mx, 32));
    float sum = 0.f;
#pragma unroll
    for (int tb = 0; tb < 4; ++tb)
#pragma unroll
      for (int i = 0; i < 4; ++i) {
        float e = __expf(sv[tb][i] - mx);
        sv[tb][i] = e;
        sum += e;
      }
    sum += __shfl_xor(sum, 16);
    sum += __shfl_xor(sum, 32);
    float inv = 1.0f / sum;

    bf16x8 pfr[2];
#pragma unroll
    for (int t = 0; t < 2; ++t) {
      f32x4 lo = {sv[2 * t][0] * inv, sv[2 * t][1] * inv, sv[2 * t][2] * inv, sv[2 * t][3] * inv};
      f32x4 hi = {sv[2 * t + 1][0] * inv, sv[2 * t + 1][1] * inv, sv[2 * t + 1][2] * inv, sv[2 * t + 1][3] * inv};
      pfr[t] = pack8(lo, hi);
    }
    f32x4 o0 = zf, o1 = zf;
    o0 = MFMA16(pfr[0], vfr[0][0], o0); o0 = MFMA16(pfr[1], vfr[1][0], o0);
    o1 = MFMA16(pfr[0], vfr[0][1], o1); o1 = MFMA16(pfr[1], vfr[1][1], o1);
#pragma unroll
    for (int i = 0; i < 4; ++i) {
      int r = qt * 16 + g * 4 + i;
      if (r < 49) {
        OALL[r * 392 + h * 32 + m16]      = f2bf(o0[i]);
        OALL[r * 392 + h * 32 + 16 + m16] = f2bf(o1[i]);
      }
    }
  }
}

__device__ __forceinline__ void proj_win(const short* __restrict__ OALL,
                                         const short* __restrict__ wpT,
                                         const float* __restrict__ pb,
                                         float* __restrict__ outw, bool valid,
                                         int u, int m16, int g) {
  const f32x4 zf = {0.f, 0.f, 0.f, 0.f};
  f32x4 pacc[4][2];
#pragma unroll
  for (int qt = 0; qt < 4; ++qt)
#pragma unroll
    for (int ct = 0; ct < 2; ++ct) pacc[qt][ct] = zf;
#pragma unroll
  for (int kk = 0; kk < 12; ++kk) {
    const int ko = kk * 32 + g * 8;
    bf16x8 af[4];
#pragma unroll
    for (int qt = 0; qt < 4; ++qt) {
      int r = qt * 16 + m16; r = r < 49 ? r : 48;
      af[qt] = *(const bf16x8*)(&OALL[r * 392 + ko]);
    }
#pragma unroll
    for (int ct = 0; ct < 2; ++ct) {
      bf16x8 bw = *(const bf16x8*)(wpT + (size_t)((u * 2 + ct) * 16 + m16) * 384 + ko);
#pragma unroll
      for (int qt = 0; qt < 4; ++qt) pacc[qt][ct] = MFMA16(af[qt], bw, pacc[qt][ct]);
    }
  }
  if (valid) {
#pragma unroll
    for (int ct = 0; ct < 2; ++ct) {
      int col = (u * 2 + ct) * 16 + m16;
      float pbv = pb[col];
#pragma unroll
      for (int qt = 0; qt < 4; ++qt)
#pragma unroll
        for (int i = 0; i < 4; ++i) {
          int r = qt * 16 + g * 4 + i;
          if (r < 49) outw[r * DIM + col] = pacc[qt][ct][i] + pbv;
        }
    }
  }
}

// 768 thr (12 waves), 1 block/CU: cap = 512/ceil(12/4) = 170 VGPR -> no spill.
__global__ __launch_bounds__(768, 1)
void fused_kernel(const float* __restrict__ xe, const float* __restrict__ xb,
                  const float* __restrict__ qb, const float* __restrict__ kvb,
                  const float* __restrict__ pb,
                  const short* __restrict__ wqT, const short* __restrict__ wkvT,
                  const short* __restrict__ wpT, const float* __restrict__ biasq,
                  float* __restrict__ out, int nwin) {
  extern __shared__ short lds[];
  const int b   = blockIdx.x;
  const int tid = threadIdx.x;
  const int u   = tid >> 6;      // 0..11 = head
  const int l   = tid & 63;
  const int m16 = l & 15;
  const int g   = l >> 4;

  const int W0 = 2 * b;
  const bool has2 = (W0 + 1) < nwin;

  // ---- stage 4 buffers: xe/xb x win0/win1 (windows contiguous in memory) ----
  for (int i = tid; i < 4 * 4704; i += 768) {
    int which = i / 4704;        // 0:xe w0, 1:xe w1, 2:xb w0, 3:xb w1
    int rem = i - which * 4704;
    int win = which & 1;
    if (win && !has2) continue;
    const float* src = (which < 2 ? xe : xb) + (size_t)(W0 + win) * (NTOK * DIM);
    short* dst = lds + (which < 2 ? 38416 + win * 19208 : win * 19208);
    int e = rem * 4;
    int r = e / DIM, c = e % DIM;
    float4 v = *(const float4*)(src + e);
    ushort4 s;
    s.x = (unsigned short)f2bf(v.x); s.y = (unsigned short)f2bf(v.y);
    s.z = (unsigned short)f2bf(v.z); s.w = (unsigned short)f2bf(v.w);
    *(ushort4*)&dst[r * 392 + c] = s;
  }
  __syncthreads();   // [#1]

  short* X0 = lds;
  short* X1 = lds + 19208;
  short* XE0 = lds + 38416;   // = OALL0 after Q(win0)
  short* XE1 = lds + 57624;   // = OALL1 after Q(win1)

  bf16x8 qfr[4];

  // ---- window 0 ----
  q_gemm(XE0, wqT, qb, u, m16, g, qfr);
  __syncthreads();   // [#2] all XE0 reads done -> XE0 becomes OALL0
  attn_head(X0, XE0, wkvT, kvb, biasq, u, m16, g, qfr);

  // ---- window 1 ----
  q_gemm(XE1, wqT, qb, u, m16, g, qfr);
  __syncthreads();   // [#3] all XE1 reads done (OALL0 writes also fenced)
  attn_head(X1, XE1, wkvT, kvb, biasq, u, m16, g, qfr);

  // ---- out-projections ----
  proj_win(XE0, wpT, pb, out + (size_t)W0 * (NTOK * DIM), true, u, m16, g);
  __syncthreads();   // [#4] OALL1 writes complete
  proj_win(XE1, wpT, pb, out + (size_t)(W0 + 1) * (NTOK * DIM), has2, u, m16, g);
}

extern "C" void kernel_launch(void* const* d_in, const int* in_sizes, int n_in,
                              void* d_out, int out_size, void* d_ws, size_t ws_size,
                              hipStream_t stream) {
  const float* xe  = (const float*)d_in[0];
  const float* xb  = (const float*)d_in[1];
  const float* qw  = (const float*)d_in[2];
  const float* qb  = (const float*)d_in[3];
  const float* kvw = (const float*)d_in[4];
  const float* kvb = (const float*)d_in[5];
  const float* pw  = (const float*)d_in[6];
  const float* pb  = (const float*)d_in[7];
  const float* bt  = (const float*)d_in[8];
  float* out = (float*)d_out;
  short* wsS = (short*)d_ws;
  float* biasq = (float*)((char*)d_ws + BIAS_BYTE_OFF);

  const int nwin = in_sizes[0] / (NTOK * DIM);

  const int prep_items = 384 * 384 + 768 * 384 + 384 * 384 + HEADS * NTOK * BIAS_RL;
  prep_kernel<<<(prep_items + 255) / 256, 256, 0, stream>>>(qw, kvw, pw, bt, wsS, biasq);

  hipFuncSetAttribute((const void*)fused_kernel,
                      hipFuncAttributeMaxDynamicSharedMemorySize, LDS_BYTES);
  const int nblk = (nwin + 1) / 2;
  fused_kernel<<<nblk, 768, LDS_BYTES, stream>>>(
      xe, xb, qb, kvb, pb,
      wsS + WQT_OFF, wsS + WKVT_OFF, wsS + WPT_OFF, biasq, out, nwin);
}

// Round 9
// 1061.999 us; speedup vs baseline: 1.0317x; 1.0136x over previous
//
#include <hip/hip_runtime.h>
#include <hip/hip_bf16.h>

#define NTOK 49
#define DIM 384
#define HEADS 12
#define SCALE 0.17677669529663687f

typedef __attribute__((ext_vector_type(8))) short bf16x8;
typedef __attribute__((ext_vector_type(4))) float f32x4;

#define MFMA16(a, b, c) __builtin_amdgcn_mfma_f32_16x16x32_bf16((a), (b), (c), 0, 0, 0)

__device__ __forceinline__ short f2bf(float f) {
  __hip_bfloat16 h = __float2bfloat16(f);
  return __builtin_bit_cast(short, h);
}

// Full-K=32 fragment from two K=16 C-tile slices (same relabel on A and B -> exact).
__device__ __forceinline__ bf16x8 pack8(f32x4 a, f32x4 b) {
  bf16x8 r;
#pragma unroll
  for (int i = 0; i < 4; ++i) { r[i] = f2bf(a[i]); r[i + 4] = f2bf(b[i]); }
  return r;
}

// ws layout:
//   wqT  : short [384][384]   elem off 0        (Wq^T row-major [n][k])
//   wkvT : short [768][384]   elem off 147456   (rows 0-383 K, 384-767 V)
//   wpT  : short [384][384]   elem off 442368
//   biasq: float [12][49][52] byte off 1179648
#define WQT_OFF   0
#define WKVT_OFF  147456
#define WPT_OFF   442368
#define BIAS_BYTE_OFF 1179648
#define BIAS_RL   52

__global__ void prep_kernel(const float* __restrict__ qw, const float* __restrict__ kvw,
                            const float* __restrict__ pw, const float* __restrict__ bt,
                            short* __restrict__ wsS, float* __restrict__ biasq) {
  int id = blockIdx.x * 256 + threadIdx.x;
  const int SZ1 = 384 * 384;
  const int SZ2 = 768 * 384;
  const int SZ3 = 384 * 384;
  if (id < SZ1) {
    int n = id / 384, k = id % 384;
    wsS[WQT_OFF + id] = f2bf(qw[k * 384 + n]);
  } else if (id < SZ1 + SZ2) {
    int t = id - SZ1; int n = t / 384, k = t % 384;
    wsS[WKVT_OFF + t] = f2bf(kvw[k * 768 + n]);
  } else if (id < SZ1 + SZ2 + SZ3) {
    int t = id - (SZ1 + SZ2); int n = t / 384, k = t % 384;
    wsS[WPT_OFF + t] = f2bf(pw[k * 384 + n]);
  } else if (id < SZ1 + SZ2 + SZ3 + HEADS * NTOK * BIAS_RL) {
    int t = id - (SZ1 + SZ2 + SZ3);
    int h = t / (NTOK * BIAS_RL); int rc = t % (NTOK * BIAS_RL);
    int q = rc / BIAS_RL, c = rc % BIAS_RL;
    float v = 0.0f;
    if (c < NTOK) {
      int idx = ((q / 7 - c / 7) + 6) * 13 + ((q % 7 - c % 7) + 6);
      v = bt[idx * HEADS + h];
    }
    biasq[t] = v;
  }
}

// LDS (shorts). Row stride 392 shorts = 196 dw == 4 mod 32: 16-row b128 frag
// reads land 2 lanes/bank (free).
#define X_OFF    0            // [49][392]  x_body
#define XE_OFF   19208        // [49][392]  x_edge; reused as OALL after Q phase
#define LDS_ELEMS 38416
#define LDS_BYTES (LDS_ELEMS * 2)   // 76832 B -> 2 blocks/CU

// hipcc launch-bounds behavior (measured R2-R8): implied caps <=128 are honored
// exactly ((512,4)->64, (384,3)->84, (384,2)->128); >128 requests fall back to
// a ~6-wave/SIMD heuristic (84). So target (384,2)->128 and fit under it.
__global__ __launch_bounds__(384, 2)
void fused_kernel(const float* __restrict__ xe, const float* __restrict__ xb,
                  const float* __restrict__ qb, const float* __restrict__ kvb,
                  const float* __restrict__ pb,
                  const short* __restrict__ wqT, const short* __restrict__ wkvT,
                  const short* __restrict__ wpT, const float* __restrict__ biasq,
                  float* __restrict__ out) {
  extern __shared__ short lds[];
  short* X    = lds + X_OFF;     // x_body
  short* XE   = lds + XE_OFF;    // x_edge
  short* OALL = XE;              // O tiles after Q phase (XE dead)

  const int b   = blockIdx.x;
  const int tid = threadIdx.x;
  const int u   = tid >> 6;      // wave 0..5, owns heads 2u, 2u+1
  const int l   = tid & 63;
  const int m16 = l & 15;
  const int g   = l >> 4;

  const f32x4 zf = {0.f, 0.f, 0.f, 0.f};

  // ---- stage x_edge -> XE and x_body -> X (bf16, 8B packed writes) ----
  const float* xew = xe + (size_t)b * (NTOK * DIM);
  const float* xbw = xb + (size_t)b * (NTOK * DIM);
  for (int i4 = tid; i4 < 2 * (NTOK * DIM / 4); i4 += 384) {
    int eb = i4 < (NTOK * DIM / 4);
    int e = (eb ? i4 : i4 - NTOK * DIM / 4) * 4;
    const float* src = eb ? xew : xbw;
    short* dst = eb ? XE : X;
    int r = e / DIM, c = e % DIM;
    float4 v = *(const float4*)(src + e);
    ushort4 s;
    s.x = (unsigned short)f2bf(v.x); s.y = (unsigned short)f2bf(v.y);
    s.z = (unsigned short)f2bf(v.z); s.w = (unsigned short)f2bf(v.w);
    *(ushort4*)&dst[r * 392 + c] = s;
  }
  __syncthreads();   // [#1]

  // ================= Q^T GEMM for heads 2u, 2u+1 (wave-private) ============
  // qc[hh][dt][tb]: C[d_local = g*4+i][tok = tb*16+m16]
  f32x4 qc[2][2][4];
#pragma unroll
  for (int hh = 0; hh < 2; ++hh)
#pragma unroll
    for (int dt = 0; dt < 2; ++dt)
#pragma unroll
      for (int tb = 0; tb < 4; ++tb) qc[hh][dt][tb] = zf;

#pragma unroll 2
  for (int kk = 0; kk < 12; ++kk) {
    const int ko = kk * 32 + g * 8;
    bf16x8 xv[4];
#pragma unroll
    for (int tb = 0; tb < 4; ++tb) {
      int tr = tb * 16 + m16; tr = tr < 49 ? tr : 48;
      xv[tb] = *(const bf16x8*)(&XE[tr * 392 + ko]);
    }
#pragma unroll
    for (int hh = 0; hh < 2; ++hh)
#pragma unroll
      for (int dt = 0; dt < 2; ++dt) {
        bf16x8 aw = *(const bf16x8*)(wqT + (size_t)((2 * u + hh) * 32 + dt * 16 + m16) * 384 + ko);
#pragma unroll
        for (int tb = 0; tb < 4; ++tb) qc[hh][dt][tb] = MFMA16(aw, xv[tb], qc[hh][dt][tb]);
      }
  }
  // fold bias+scale, merge dt slices into full-K frags; lane m16 = q
  bf16x8 qfr[2][4];
#pragma unroll
  for (int hh = 0; hh < 2; ++hh) {
    const int h = 2 * u + hh;
    float4 t0 = *(const float4*)(qb + h * 32 + g * 4);
    float4 t1 = *(const float4*)(qb + h * 32 + 16 + g * 4);
    f32x4 b0 = {t0.x, t0.y, t0.z, t0.w};
    f32x4 b1 = {t1.x, t1.y, t1.z, t1.w};
#pragma unroll
    for (int qt = 0; qt < 4; ++qt)
      qfr[hh][qt] = pack8((qc[hh][0][qt] + b0) * SCALE, (qc[hh][1][qt] + b1) * SCALE);
  }
  __syncthreads();   // [#2] all XE reads done -> XE becomes OALL

  // ================= per head: K GEMM, V GEMM (split passes), attention =====
#pragma unroll 1
  for (int hh = 0; hh < 2; ++hh) {
    const int h = 2 * u + hh;

    // ---- K pass (kc only: 32 VGPRs live) ----
    bf16x8 kfr[4];
    {
      f32x4 kc[2][4];
#pragma unroll
      for (int dt = 0; dt < 2; ++dt)
#pragma unroll
        for (int tb = 0; tb < 4; ++tb) kc[dt][tb] = zf;
#pragma unroll 2
      for (int kk = 0; kk < 12; ++kk) {
        const int ko = kk * 32 + g * 8;
        bf16x8 xv[4];
#pragma unroll
        for (int tb = 0; tb < 4; ++tb) {
          int tr = tb * 16 + m16; tr = tr < 49 ? tr : 48;
          xv[tb] = *(const bf16x8*)(&X[tr * 392 + ko]);
        }
        bf16x8 kw[2];
#pragma unroll
        for (int dt = 0; dt < 2; ++dt)
          kw[dt] = *(const bf16x8*)(wkvT + (size_t)(h * 32 + dt * 16 + m16) * 384 + ko);
#pragma unroll
        for (int dt = 0; dt < 2; ++dt)
#pragma unroll
          for (int tb = 0; tb < 4; ++tb) kc[dt][tb] = MFMA16(kw[dt], xv[tb], kc[dt][tb]);
      }
      float4 t0 = *(const float4*)(kvb + h * 32 + g * 4);
      float4 t1 = *(const float4*)(kvb + h * 32 + 16 + g * 4);
      f32x4 b0 = {t0.x, t0.y, t0.z, t0.w};
      f32x4 b1 = {t1.x, t1.y, t1.z, t1.w};
#pragma unroll
      for (int tb = 0; tb < 4; ++tb) kfr[tb] = pack8(kc[0][tb] + b0, kc[1][tb] + b1);
    }

    // ---- V pass (vc only: 32 VGPRs live) ----
    bf16x8 vfr[2][2];
    {
      f32x4 vc[4][2];
#pragma unroll
      for (int tb = 0; tb < 4; ++tb)
#pragma unroll
        for (int db = 0; db < 2; ++db) vc[tb][db] = zf;
#pragma unroll 2
      for (int kk = 0; kk < 12; ++kk) {
        const int ko = kk * 32 + g * 8;
        bf16x8 xv[4];
#pragma unroll
        for (int tb = 0; tb < 4; ++tb) {
          int tr = tb * 16 + m16; tr = tr < 49 ? tr : 48;
          xv[tb] = *(const bf16x8*)(&X[tr * 392 + ko]);
        }
        bf16x8 vw[2];
#pragma unroll
        for (int db = 0; db < 2; ++db)
          vw[db] = *(const bf16x8*)(wkvT + (size_t)(384 + h * 32 + db * 16 + m16) * 384 + ko);
#pragma unroll
        for (int tb = 0; tb < 4; ++tb)
#pragma unroll
          for (int db = 0; db < 2; ++db) vc[tb][db] = MFMA16(xv[tb], vw[db], vc[tb][db]);
      }
#pragma unroll
      for (int db = 0; db < 2; ++db) {
        float vbv = kvb[384 + h * 32 + db * 16 + m16];
        f32x4 bv = {vbv, vbv, vbv, vbv};
#pragma unroll
        for (int t = 0; t < 2; ++t)
          vfr[t][db] = pack8(vc[2 * t][db] + bv, vc[2 * t + 1][db] + bv);
      }
    }

    // ---- attention per q-tile: S (1 MFMA/k-tile), softmax, PV ----
#pragma unroll
    for (int qt = 0; qt < 4; ++qt) {
      int q = qt * 16 + m16; int qcl = q < 49 ? q : 48;
      const float* bq = biasq + (size_t)(h * NTOK + qcl) * BIAS_RL;
      f32x4 s[4];
#pragma unroll
      for (int tb = 0; tb < 4; ++tb) s[tb] = MFMA16(kfr[tb], qfr[hh][qt], zf);

      float sv[4][4];
      float mx = -3.0e38f;
#pragma unroll
      for (int tb = 0; tb < 4; ++tb) {
        int k0 = tb * 16 + g * 4;
        int kcl = k0 <= 48 ? k0 : 48;     // bias row padded to 52
        float4 bv = *(const float4*)(bq + kcl);
        sv[tb][0] = (k0 + 0 < 49) ? s[tb][0] + bv.x : -3.0e38f;
        sv[tb][1] = (k0 + 1 < 49) ? s[tb][1] + bv.y : -3.0e38f;
        sv[tb][2] = (k0 + 2 < 49) ? s[tb][2] + bv.z : -3.0e38f;
        sv[tb][3] = (k0 + 3 < 49) ? s[tb][3] + bv.w : -3.0e38f;
        mx = fmaxf(mx, fmaxf(fmaxf(sv[tb][0], sv[tb][1]), fmaxf(sv[tb][2], sv[tb][3])));
      }
      mx = fmaxf(mx, __shfl_xor(mx, 16));
      mx = fmaxf(mx, __shfl_xor(mx, 32));
      float sum = 0.f;
#pragma unroll
      for (int tb = 0; tb < 4; ++tb)
#pragma unroll
        for (int i = 0; i < 4; ++i) {
          float e = __expf(sv[tb][i] - mx);
          sv[tb][i] = e;
          sum += e;
        }
      sum += __shfl_xor(sum, 16);
      sum += __shfl_xor(sum, 32);
      float inv = 1.0f / sum;

      bf16x8 pfr[2];
#pragma unroll
      for (int t = 0; t < 2; ++t) {
        f32x4 lo = {sv[2 * t][0] * inv, sv[2 * t][1] * inv, sv[2 * t][2] * inv, sv[2 * t][3] * inv};
        f32x4 hi = {sv[2 * t + 1][0] * inv, sv[2 * t + 1][1] * inv, sv[2 * t + 1][2] * inv, sv[2 * t + 1][3] * inv};
        pfr[t] = pack8(lo, hi);
      }
      f32x4 o0 = zf, o1 = zf;
      o0 = MFMA16(pfr[0], vfr[0][0], o0); o0 = MFMA16(pfr[1], vfr[1][0], o0);
      o1 = MFMA16(pfr[0], vfr[0][1], o1); o1 = MFMA16(pfr[1], vfr[1][1], o1);
#pragma unroll
      for (int i = 0; i < 4; ++i) {
        int r = qt * 16 + g * 4 + i;
        if (r < 49) {
          OALL[r * 392 + h * 32 + m16]      = f2bf(o0[i]);
          OALL[r * 392 + h * 32 + 16 + m16] = f2bf(o1[i]);
        }
      }
    }
  }
  __syncthreads();   // [#3] OALL complete

  // ================= out-projection: wave owns col-tiles u*4..u*4+3 ========
  f32x4 pacc[4][4];
#pragma unroll
  for (int qt = 0; qt < 4; ++qt)
#pragma unroll
    for (int ct = 0; ct < 4; ++ct) pacc[qt][ct] = zf;
#pragma unroll 2
  for (int kk = 0; kk < 12; ++kk) {
    const int ko = kk * 32 + g * 8;
    bf16x8 af[4];
#pragma unroll
    for (int qt = 0; qt < 4; ++qt) {
      int r = qt * 16 + m16; r = r < 49 ? r : 48;
      af[qt] = *(const bf16x8*)(&OALL[r * 392 + ko]);
    }
#pragma unroll
    for (int ct = 0; ct < 4; ++ct) {
      bf16x8 bw = *(const bf16x8*)(wpT + (size_t)((u * 4 + ct) * 16 + m16) * 384 + ko);
#pragma unroll
      for (int qt = 0; qt < 4; ++qt) pacc[qt][ct] = MFMA16(af[qt], bw, pacc[qt][ct]);
    }
  }
  float* outw = out + (size_t)b * (NTOK * DIM);
#pragma unroll
  for (int ct = 0; ct < 4; ++ct) {
    int col = (u * 4 + ct) * 16 + m16;
    float pbv = pb[col];
#pragma unroll
    for (int qt = 0; qt < 4; ++qt)
#pragma unroll
      for (int i = 0; i < 4; ++i) {
        int r = qt * 16 + g * 4 + i;
        if (r < 49) outw[r * DIM + col] = pacc[qt][ct][i] + pbv;
      }
  }
}

extern "C" void kernel_launch(void* const* d_in, const int* in_sizes, int n_in,
                              void* d_out, int out_size, void* d_ws, size_t ws_size,
                              hipStream_t stream) {
  const float* xe  = (const float*)d_in[0];
  const float* xb  = (const float*)d_in[1];
  const float* qw  = (const float*)d_in[2];
  const float* qb  = (const float*)d_in[3];
  const float* kvw = (const float*)d_in[4];
  const float* kvb = (const float*)d_in[5];
  const float* pw  = (const float*)d_in[6];
  const float* pb  = (const float*)d_in[7];
  const float* bt  = (const float*)d_in[8];
  float* out = (float*)d_out;
  short* wsS = (short*)d_ws;
  float* biasq = (float*)((char*)d_ws + BIAS_BYTE_OFF);

  const int nwin = in_sizes[0] / (NTOK * DIM);

  const int prep_items = 384 * 384 + 768 * 384 + 384 * 384 + HEADS * NTOK * BIAS_RL;
  prep_kernel<<<(prep_items + 255) / 256, 256, 0, stream>>>(qw, kvw, pw, bt, wsS, biasq);

  hipFuncSetAttribute((const void*)fused_kernel,
                      hipFuncAttributeMaxDynamicSharedMemorySize, LDS_BYTES);
  fused_kernel<<<nwin, 384, LDS_BYTES, stream>>>(
      xe, xb, qb, kvb, pb,
      wsS + WQT_OFF, wsS + WKVT_OFF, wsS + WPT_OFF, biasq, out);
}